// Round 7
// baseline (165.626 us; speedup 1.0000x reference)
//
#include <hip/hip_runtime.h>

// TopologyNetwork: B=1024, N=5000, K=16, 9 levels.
// R20 = R13's exact rolled-loop structure, halved column group for 2x occupancy:
//  - Evidence: R14-R19 all regressed vs R13 (conflict matching, manual
//    pipelining, 2-node ILP). Fixed overhead bench-k_fused = 67+-2us every
//    round. k_fused accounting: LDS pipe busy only ~11K of 18K cyc/level ->
//    ~35% pipe-idle from barrier convoys + level-start latency. Occupancy
//    never tested: always 1 block/CU (16 waves, 40% duty).
//  - Fix: CPG=2, grid=512 -> 2 independent blocks/CU (32 waves); blocks fill
//    each other's barrier/latency gaps. __launch_bounds__(1024,8) caps VGPR
//    at 64 so both blocks resident. LDS 40,448 B/block.
//  - Gather = ds_read_b32 (f16x2 = 2 cols), 1 pk_fma/edge. Inner loop is
//    R13's rolled shape (the champion schedule).
//  - pack: pe[j] = ((l&1)*20224 + s*4) | f16(w)<<16 -> read base is constant
//    0, 1 v_and per edge. Biases pre-packed f16x2.
//  - Risk (stated): per-XCD L2 edge BW ~3.7 of ~4.3 TB/s ceiling. If L2
//    binds, time stays ~60-65 -> structure ceiling confirmed.

#define TB 1024
#define TN 5000
#define TK 16
#define TLV 9
#define CPG 2                   // f16 cols per group (4 B per node-row)
#define NG  (TB / CPG)          // 512 col-groups = grid (2 blocks/CU)
#define LT  1024                // threads per block (16 waves)
#define PEL (TN * TK)           // u32 per level in packed-edge array

#define SLOTP 5056              // u32 slots per parity (pad 5000 -> x16)
#define PBYTES (SLOTP * 4)      // 20224 B per parity; total LDS 40448 B

typedef unsigned int u32;
typedef unsigned short u16;
typedef _Float16 h2 __attribute__((ext_vector_type(2)));

__device__ __forceinline__ h2 u2h(u32 v) { return __builtin_bit_cast(h2, v); }
__device__ __forceinline__ u32 h2u(h2 h) { return __builtin_bit_cast(u32, h); }
__device__ __forceinline__ u32 packf(float a, float b) {
    h2 h; h.x = (_Float16)a; h.y = (_Float16)b;
    return h2u(h);
}

// ---- pack: elementwise, fully coalesced ----
// pe[j] = ((l&1)*PBYTES + s*4) | f16(w)<<16 ; b2[l*TN+n] = packf(bias,bias)
__global__ __launch_bounds__(256) void k_pack(
    const int* __restrict__ idx, const float* __restrict__ w,
    const float* __restrict__ biases,
    u32* __restrict__ pe, u32* __restrict__ b2)
{
    const int j = blockIdx.x * 256 + threadIdx.x;
    if (j < TLV * TN * TK) {
        const int l = j / (TN * TK);
        const u32 s = (u32)idx[j];
        h2 hw; hw.x = (_Float16)w[j]; hw.y = (_Float16)0.0f;
        pe[j] = ((u32)(l & 1) * (u32)PBYTES + s * 4u) | (h2u(hw) << 16);
    }
    if (j < TLV * TN) {
        const float b = biases[j];
        b2[j] = packf(b, b);
    }
}

// ---- fused: transpose-in + 9 levels in LDS + transpose-out ----
__global__ __launch_bounds__(LT, 8) void k_fused(
    const float* __restrict__ x,      // [B,N]
    float* __restrict__ out,          // [B,N]
    const u32* __restrict__ pe,       // [LV][TN][TK] (byteoff | f16w<<16)
    const u32* __restrict__ b2)       // [LV][TN] packed f16x2 biases
{
    __shared__ u32 buf[2 * SLOTP];    // 40,448 B ping-pong (f16x2 per node)
    const char* lds = reinterpret_cast<const char*>(buf);
    const int g = blockIdx.x;
    const int t = threadIdx.x;

    // stage x cols 2g, 2g+1 as f16x2 rows into parity 0
    {
        const float* xp0 = x + (size_t)(g * CPG + 0) * TN;
        const float* xp1 = x + (size_t)(g * CPG + 1) * TN;
        for (int n = t; n < TN; n += LT)
            buf[n] = packf(xp0[n], xp1[n]);
    }
    __syncthreads();

    int cur = 0;
    for (int l = 0; l < TLV; ++l) {
        const u32* ep_l = pe + (size_t)l * PEL;
        const u32* b_l  = b2 + (size_t)l * TN;
        u32* wb = buf + (cur ^ 1) * SLOTP;
        for (int n = t; n < TN; n += LT) {
            // 16 edges of node n: 64 B contiguous -> 4x dwordx4
            const uint4* ep = reinterpret_cast<const uint4*>(ep_l + (size_t)n * TK);
            const uint4 e0 = ep[0];
            const uint4 e1 = ep[1];
            const uint4 e2 = ep[2];
            const uint4 e3 = ep[3];
            const u32 es[TK] = {e0.x, e0.y, e0.z, e0.w,
                                e1.x, e1.y, e1.z, e1.w,
                                e2.x, e2.y, e2.z, e2.w,
                                e3.x, e3.y, e3.z, e3.w};

            u32 acc = b_l[n];                          // bias in both halves

            #pragma unroll
            for (int k = 0; k < TK; ++k) {
                const u32 e   = es[k];
                const u32 off = e & 0xffffu;           // parity-baked byte off
                const u32 av  = *reinterpret_cast<const u32*>(lds + off);
                // acc += w(hi16 of e) * av : weight broadcast via op_sel
                asm("v_pk_fma_f16 %0, %1, %2, %0 op_sel:[1,0,0] op_sel_hi:[1,1,1]"
                    : "+v"(acc) : "v"(e), "v"(av));
            }

            // LeakyReLU(0.1) = max(x, 0.1*x)
            h2 A = u2h(acc);
            h2 tenth; tenth.x = (_Float16)0.1f; tenth.y = (_Float16)0.1f;
            A = __builtin_elementwise_max(A, A * tenth);
            wb[n] = h2u(A);
        }
        __syncthreads();
        cur ^= 1;
    }

    // write out cols 2g, 2g+1 (parity 1 holds level-8 results)
    {
        float* op0 = out + (size_t)(g * CPG + 0) * TN;
        float* op1 = out + (size_t)(g * CPG + 1) * TN;
        for (int n = t; n < TN; n += LT) {
            const h2 h = u2h(buf[SLOTP + n]);
            op0[n] = (float)h.x;
            op1[n] = (float)h.y;
        }
    }
}

extern "C" void kernel_launch(void* const* d_in, const int* in_sizes, int n_in,
                              void* d_out, int out_size, void* d_ws, size_t ws_size,
                              hipStream_t stream)
{
    const float* x       = (const float*)d_in[0];   // [B,N]
    const int*   src_idx = (const int*)  d_in[1];   // [LV,N,K]
    const float* weights = (const float*)d_in[2];   // [LV,N,K]
    const float* biases  = (const float*)d_in[3];   // [LV,N]
    float* out = (float*)d_out;                     // [B,N]

    u32* pe = (u32*)d_ws;                           // [LV][TN][TK] = 2.88 MB
    u32* b2 = pe + (size_t)TLV * TN * TK;           // [LV][TN]     = 180 KB

    // pack (elementwise, fully coalesced)
    {
        const int ne = TLV * TN * TK;               // 720000
        hipLaunchKernelGGL(k_pack, dim3((ne + 255) / 256), dim3(256), 0, stream,
                           src_idx, weights, biases, pe, b2);
    }
    // fused 9-level evaluation, 2 blocks/CU
    hipLaunchKernelGGL(k_fused, dim3(NG), dim3(LT), 0, stream,
                       x, out, pe, b2);
}

// Round 8
// 127.520 us; speedup vs baseline: 1.2988x; 1.2988x over previous
//
#include <hip/hip_runtime.h>

// TopologyNetwork: B=1024, N=5000, K=16, 9 levels.
// R21 = R13 restored (the 8-round champion) + three validated micro-shaves:
//  - CPG=4 / grid=256 / 1 block/CU / 16 waves / rolled inner loop: every
//    structural deviation measured and regressed (R14-R20): conflict
//    matching dt=0, cuckoo dt=0 (+32us pack), reg pipelining +6us,
//    2-node ILP +7us, 2x occupancy via CPG=2 +41us (2x LDS instr).
//  - Shave (a): 9 unrolled level bodies -> read parity is a compile-time
//    constant folded into the ds_read 16-bit imm (offset:40448); kills the
//    per-edge base v_add. Inner loop body is R13's byte-for-byte.
//  - Shave (b): biases pre-packed f16x2 in k_pack (no per-node cvt).
//  - Shave (c): pack stores s*8 in low16 (1 v_and per edge total).

#define TB 1024
#define TN 5000
#define TK 16
#define TLV 9
#define CPG 4                   // f16 cols per group (8 B per node-row)
#define NG  (TB / CPG)          // 256 col-groups = grid (1 block/CU)
#define LT  1024                // threads per block (16 waves)
#define PEL (TN * TK)           // u32 per level in packed-edge array

#define PSTRIDE 40448           // bytes per parity (5056 nodes x 8 B)

typedef unsigned int u32;
typedef unsigned short u16;
typedef _Float16 h2 __attribute__((ext_vector_type(2)));

__device__ __forceinline__ h2 u2h(u32 v) { return __builtin_bit_cast(h2, v); }
__device__ __forceinline__ u32 h2u(h2 h) { return __builtin_bit_cast(u32, h); }
__device__ __forceinline__ u32 packf(float a, float b) {
    h2 h; h.x = (_Float16)a; h.y = (_Float16)b;
    return h2u(h);
}

// ---- pack: elementwise, fully coalesced ----
// pe[j] = (s*8) | f16(w)<<16 ; b2[l*TN+n] = packf(bias,bias)
__global__ __launch_bounds__(256) void k_pack(
    const int* __restrict__ idx, const float* __restrict__ w,
    const float* __restrict__ biases,
    u32* __restrict__ pe, u32* __restrict__ b2)
{
    const int j = blockIdx.x * 256 + threadIdx.x;
    if (j < TLV * TN * TK) {
        const u32 s = (u32)idx[j];
        h2 hw; hw.x = (_Float16)w[j]; hw.y = (_Float16)0.0f;
        pe[j] = (s * 8u) | (h2u(hw) << 16);
    }
    if (j < TLV * TN) {
        const float b = biases[j];
        b2[j] = packf(b, b);
    }
}

// ---- fused: transpose-in + 9 levels in LDS + transpose-out ----
// One level: R13's rolled node loop; RP/WP are compile-time byte constants,
// so the read parity folds into the ds_read immediate offset.
#define LEVEL(LIDX, RP, WP) do {                                              \
    const u32* ep_l = pe + (size_t)(LIDX) * PEL;                              \
    const u32* b_l  = b2 + (size_t)(LIDX) * TN;                               \
    for (int n = t; n < TN; n += LT) {                                        \
        const uint4* ep = reinterpret_cast<const uint4*>(ep_l + (size_t)n * TK);\
        const uint4 e0 = ep[0];                                               \
        const uint4 e1 = ep[1];                                               \
        const uint4 e2 = ep[2];                                               \
        const uint4 e3 = ep[3];                                               \
        const u32 es[TK] = {e0.x, e0.y, e0.z, e0.w,                           \
                            e1.x, e1.y, e1.z, e1.w,                           \
                            e2.x, e2.y, e2.z, e2.w,                           \
                            e3.x, e3.y, e3.z, e3.w};                          \
        u32 a01 = b_l[n];                      /* f16x2 bias, both halves */  \
        u32 a23 = a01;                                                        \
        _Pragma("unroll")                                                     \
        for (int k = 0; k < TK; ++k) {                                        \
            const u32 e   = es[k];                                            \
            const u32 off = e & 0xffffu;       /* s*8 byte offset */          \
            const uint2 av =                                                  \
                *reinterpret_cast<const uint2*>(lds + (RP) + off);            \
            asm("v_pk_fma_f16 %0, %1, %2, %0 op_sel:[1,0,0] op_sel_hi:[1,1,1]"\
                : "+v"(a01) : "v"(e), "v"(av.x));                             \
            asm("v_pk_fma_f16 %0, %1, %2, %0 op_sel:[1,0,0] op_sel_hi:[1,1,1]"\
                : "+v"(a23) : "v"(e), "v"(av.y));                             \
        }                                                                     \
        h2 A = u2h(a01), Bv = u2h(a23);                                       \
        h2 tenth; tenth.x = (_Float16)0.1f; tenth.y = (_Float16)0.1f;         \
        A  = __builtin_elementwise_max(A,  A  * tenth);                       \
        Bv = __builtin_elementwise_max(Bv, Bv * tenth);                       \
        uint2 r; r.x = h2u(A); r.y = h2u(Bv);                                 \
        *reinterpret_cast<uint2*>(lds + (WP) + (size_t)n * 8) = r;            \
    }                                                                         \
    __syncthreads();                                                          \
} while (0)

__global__ __launch_bounds__(LT) void k_fused(
    const float* __restrict__ x,      // [B,N]
    float* __restrict__ out,          // [B,N]
    const u32* __restrict__ pe,       // [LV][TN][TK] (s*8 | f16w<<16)
    const u32* __restrict__ b2)       // [LV][TN] packed f16x2 biases
{
    __shared__ char lds[2 * PSTRIDE]; // 80,896 B ping-pong
    const int g = blockIdx.x;
    const int t = threadIdx.x;

    // stage x cols g*4..g*4+3 as f16 rows into parity 0
    {
        const float* xp0 = x + (size_t)(g * CPG + 0) * TN;
        const float* xp1 = x + (size_t)(g * CPG + 1) * TN;
        const float* xp2 = x + (size_t)(g * CPG + 2) * TN;
        const float* xp3 = x + (size_t)(g * CPG + 3) * TN;
        for (int n = t; n < TN; n += LT) {
            uint2 v;
            v.x = packf(xp0[n], xp1[n]);
            v.y = packf(xp2[n], xp3[n]);
            *reinterpret_cast<uint2*>(lds + (size_t)n * 8) = v;
        }
    }
    __syncthreads();

    // 9 levels; parity alternates, compile-time per body.
    LEVEL(0, 0,       PSTRIDE);
    LEVEL(1, PSTRIDE, 0);
    LEVEL(2, 0,       PSTRIDE);
    LEVEL(3, PSTRIDE, 0);
    LEVEL(4, 0,       PSTRIDE);
    LEVEL(5, PSTRIDE, 0);
    LEVEL(6, 0,       PSTRIDE);
    LEVEL(7, PSTRIDE, 0);
    LEVEL(8, 0,       PSTRIDE);

    // write out cols g*4..g*4+3 (parity 1 holds level-8 results)
    {
        float* op0 = out + (size_t)(g * CPG + 0) * TN;
        float* op1 = out + (size_t)(g * CPG + 1) * TN;
        float* op2 = out + (size_t)(g * CPG + 2) * TN;
        float* op3 = out + (size_t)(g * CPG + 3) * TN;
        for (int n = t; n < TN; n += LT) {
            const uint2 v =
                *reinterpret_cast<const uint2*>(lds + PSTRIDE + (size_t)n * 8);
            h2 h;
            h = u2h(v.x); op0[n] = (float)h.x; op1[n] = (float)h.y;
            h = u2h(v.y); op2[n] = (float)h.x; op3[n] = (float)h.y;
        }
    }
}

extern "C" void kernel_launch(void* const* d_in, const int* in_sizes, int n_in,
                              void* d_out, int out_size, void* d_ws, size_t ws_size,
                              hipStream_t stream)
{
    const float* x       = (const float*)d_in[0];   // [B,N]
    const int*   src_idx = (const int*)  d_in[1];   // [LV,N,K]
    const float* weights = (const float*)d_in[2];   // [LV,N,K]
    const float* biases  = (const float*)d_in[3];   // [LV,N]
    float* out = (float*)d_out;                     // [B,N]

    u32* pe = (u32*)d_ws;                           // [LV][TN][TK] = 2.88 MB
    u32* b2 = pe + (size_t)TLV * TN * TK;           // [LV][TN]     = 180 KB

    // pack (elementwise, fully coalesced)
    {
        const int ne = TLV * TN * TK;               // 720000
        hipLaunchKernelGGL(k_pack, dim3((ne + 255) / 256), dim3(256), 0, stream,
                           src_idx, weights, biases, pe, b2);
    }
    // fused 9-level evaluation, 1 block/CU
    hipLaunchKernelGGL(k_fused, dim3(NG), dim3(LT), 0, stream,
                       x, out, pe, b2);
}